// Round 12
// baseline (95.963 us; speedup 1.0000x reference)
//
#include <hip/hip_runtime.h>
#include <hip/hip_bf16.h>

#define NFFT    1024
#define HOPSZ   256
#define XLEN    262144
#define PADLEN  (XLEN + NFFT)      // 263168
#define NBATCH  16
#define NBINS2  1026
#define FBIN    513
#define NFRAMES 1025
#define NGF     (NBATCH * NFRAMES) // 16400
#define TOTOUT  ((size_t)NBATCH * FBIN * NFRAMES)

// GEMM geometry: 256 gf x 256 bins per block, BK=64, 8 waves (2 frame-halves x 4 bin-quarters)
#define KT 64
#define NKT 16
#define NT_TILES 64                // gf tiles
#define MT_TILES 4                 // bin tiles
#define NWG (MT_TILES * NT_TILES)  // 256
#define ABYTES 32768               // W region bytes per buffer (X region follows)
#define BUFE   32768
#define BUFB   65536
#define NTAIL  49184               // 2*16400 + 16*1024
#define LDS_BYTES (2 * BUFB)       // 131072

// prep kernel block ranges (256 threads each)
#define PX_BLKS 2056               // NBATCH*PADLEN/8/256
#define PW_BLKS 1026               // NBINS2*NFFT/4/256
#define TL_BLKS 12296              // NTAIL/4
#define PREP_BLKS (PX_BLKS + PW_BLKS + TL_BLKS)

typedef short bf16x8 __attribute__((ext_vector_type(8)));
typedef float f32x4  __attribute__((ext_vector_type(4)));
typedef float f32x4u __attribute__((ext_vector_type(4), aligned(4)));
typedef unsigned short u16x8 __attribute__((ext_vector_type(8)));
typedef unsigned short u16x4 __attribute__((ext_vector_type(4)));

__device__ __forceinline__ unsigned short f2bf(float f) {
  union { float f; unsigned u; } v; v.f = f;
  unsigned r = v.u + 0x7fffu + ((v.u >> 16) & 1u);   // RNE
  return (unsigned short)(r >> 16);
}

typedef __attribute__((address_space(1))) void void_g;
typedef __attribute__((address_space(3))) void void_l;
__device__ __forceinline__ void gload_lds16(const void* g, void* l) {
  __builtin_amdgcn_global_load_lds((void_g*)(g), (void_l*)(l), 16, 0, 0);
}

// ---- fused prep: pack_x | pack_w | tail (tail reads f32 originals, exact) ----
__global__ __launch_bounds__(256) void prep_kernel(const float* __restrict__ x,
                                                   const float* __restrict__ W,
                                                   unsigned short* __restrict__ xp,
                                                   unsigned short* __restrict__ wb,
                                                   float* __restrict__ out) {
  const int bid = blockIdx.x;
  const int tid = threadIdx.x;

  if (bid < PX_BLKS) {
    // ---- pack x -> bf16 with center padding ----
    long long base = ((long long)bid * 256 + tid) * 8;
    int b   = (int)(base / PADLEN);
    int pos = (int)(base % PADLEN);
    const float* xb = x + (long long)b * XLEN;
    u16x8 v;
#pragma unroll
    for (int j = 0; j < 8; ++j) {
      int xi = pos + j - (NFFT / 2);
      float f = ((unsigned)xi < (unsigned)XLEN) ? xb[xi] : 0.0f;
      v[j] = f2bf(f);
    }
    *reinterpret_cast<u16x8*>(xp + base) = v;
    return;
  }
  if (bid < PX_BLKS + PW_BLKS) {
    // ---- pack W -> bf16 ----
    long long t = (((long long)(bid - PX_BLKS)) * 256 + tid) * 4;
    float4 f = *reinterpret_cast<const float4*>(W + t);
    u16x4 v;
    v[0] = f2bf(f.x); v[1] = f2bf(f.y); v[2] = f2bf(f.z); v[3] = f2bf(f.w);
    *reinterpret_cast<u16x4*>(wb + t) = v;
    return;
  }
  // ---- tail: wave-per-output, exact f32 ----
  {
    const int wid = (bid - PX_BLKS - PW_BLKS) * 4 + (tid >> 6);
    const int l   = tid & 63;
    int bin, gf;
    if (wid < 2 * NGF) { bin = 1024 + (wid & 1); gf = wid >> 1; }
    else { const int s = wid - 2 * NGF; gf = 16384 + (s & 15); bin = s >> 4; }
    const int bb = gf / NFRAMES;
    const int fr = gf - bb * NFRAMES;
    const float* xb = x + (size_t)bb * XLEN;
    const float* wrow = W + (size_t)bin * NFFT + l * 16;
    const int base = fr * HOPSZ - (NFFT / 2) + l * 16;
    float s0 = 0.f;
    if (fr >= 2 && fr <= 1022) {       // window fully in-bounds (wave-uniform)
#pragma unroll
      for (int q = 0; q < 4; ++q) {
        float4 xv = *reinterpret_cast<const float4*>(xb + base + q * 4);
        float4 wv = *reinterpret_cast<const float4*>(wrow + q * 4);
        s0 = fmaf(xv.x, wv.x, s0); s0 = fmaf(xv.y, wv.y, s0);
        s0 = fmaf(xv.z, wv.z, s0); s0 = fmaf(xv.w, wv.w, s0);
      }
    } else {
#pragma unroll
      for (int j = 0; j < 16; ++j) {
        int xi = base + j;
        float xv = ((unsigned)xi < (unsigned)XLEN) ? xb[xi] : 0.f;
        s0 = fmaf(xv, wrow[j], s0);
      }
    }
#pragma unroll
    for (int k = 32; k >= 1; k >>= 1) s0 += __shfl_xor(s0, k);
    if (l == 0) {
      size_t off;
      if (bin < FBIN) off = ((size_t)bb * FBIN + bin) * NFRAMES + fr;
      else            off = TOTOUT + ((size_t)bb * FBIN + (bin - FBIN)) * NFRAMES + fr;
      out[off] = s0;
    }
  }
}

// ---- 256x256 GEMM, r9 K-loop, SWAPPED operands (X as A-operand, W as B) so
//      D row=frame, col=bin -> per-lane f32x4 = 4 consecutive frames of one bin
//      -> direct dwordx4 epilogue, NO LDS patch ----
__global__ __launch_bounds__(512, 2) void stft_mfma8_kernel(const unsigned short* __restrict__ Xp,
                                                            const unsigned short* __restrict__ Wb,
                                                            float* __restrict__ out) {
  extern __shared__ unsigned short lds[];
  const int tid = threadIdx.x;
  const int l   = tid & 63;
  const int w   = tid >> 6;        // 0..7
  const int wr  = w >> 2;          // frame half (128 frames)
  const int wc  = w & 3;           // bin quarter (64 bins)
  const int r16 = l & 15, hi = l >> 4;

  // XCD swizzle
  const int bid = blockIdx.x;
  const int c_  = bid >> 3;
  const int nt  = (bid & 7) * 8 + (c_ & 7);
  const int mt  = c_ >> 3;
  const int bin0 = mt * 256;
  const int gf0  = nt * 256;

  // staging (pre-swizzled global source), r9-proven addressing
  const int lr = l >> 3;
  const int ls = l & 7;
  const int cswz = ((ls ^ lr) << 3);

  unsigned aqoff[4];
#pragma unroll
  for (int qi = 0; qi < 4; ++qi)
    aqoff[qi] = (unsigned)(bin0 + qi * 64 + w * 8 + lr) * NFFT + cswz;
  unsigned boff[4];
#pragma unroll
  for (int j = 0; j < 4; ++j) {
    const int gf = gf0 + (w * 4 + j) * 8 + lr;     // < 16384
    const int bb = gf / NFRAMES;
    const int fr = gf - bb * NFRAMES;
    boff[j] = (unsigned)bb * PADLEN + (unsigned)fr * HOPSZ + cswz;
  }

#define STAGE(D, KC) do { \
    _Pragma("unroll") \
    for (int q_ = 0; q_ < 4; ++q_) \
      gload_lds16(Wb + aqoff[q_] + (KC), lds + (D) * BUFE + q_ * 4096 + w * 512); \
    _Pragma("unroll") \
    for (int j_ = 0; j_ < 4; ++j_) \
      gload_lds16(Xp + boff[j_] + (KC), lds + (D) * BUFE + 16384 + (w * 4 + j_) * 512); \
    } while (0)

  // fragment read bases (T2 XOR-swizzle); A-operand = X region (at ABYTES),
  // B-operand = W region (at 0)
  const int xB0 = ABYTES + (wr * 128 + r16) * 128;   // frames
  const int wB0 = (wc * 64 + r16) * 128;             // bins
  const int swz = (r16 & 7) << 4;
  const int c0  = (hi * 16) ^ swz;
  const int c1  = (64 + hi * 16) ^ swz;

// 12 ds_reads: 4 W frags + 8 X frags
#define RD12(BASE, C, XARR, WARR) do { \
    _Pragma("unroll") \
    for (int n_ = 0; n_ < 4; ++n_) \
      WARR[n_] = *reinterpret_cast<const bf16x8*>((const char*)(BASE) + wB0 + n_ * 2048 + (C)); \
    _Pragma("unroll") \
    for (int m_ = 0; m_ < 8; ++m_) \
      XARR[m_] = *reinterpret_cast<const bf16x8*>((const char*)(BASE) + xB0 + m_ * 2048 + (C)); \
    } while (0)

#define MFMA32(XARR, WARR) do { \
    __builtin_amdgcn_s_setprio(1); \
    _Pragma("unroll") \
    for (int m_ = 0; m_ < 8; ++m_) { \
      _Pragma("unroll") \
      for (int n_ = 0; n_ < 4; ++n_) \
        acc[m_][n_] = __builtin_amdgcn_mfma_f32_16x16x32_bf16(XARR[m_], WARR[n_], acc[m_][n_], 0, 0, 0); \
    } \
    __builtin_amdgcn_s_setprio(0); } while (0)

  f32x4 acc[8][4] = {};
  bf16x8 X0[8], W0[4], X1[8], W1[4];

  // ---- prologue: stage kt0->buf0, kt1->buf1; kt0 visible; read (buf0,ks0) ----
  STAGE(0, 0);
  STAGE(1, KT);
  asm volatile("s_waitcnt vmcnt(8)" ::: "memory");
  __builtin_amdgcn_s_barrier();
  __builtin_amdgcn_sched_barrier(0);
  RD12(lds, c0, X0, W0);

#pragma unroll 1
  for (int t = 0; t < NKT; ++t) {
    const int ci = t & 1;
    const char* cbuf = (const char*)lds + ci * BUFB;
    const char* nbuf = (const char*)lds + (ci ^ 1) * BUFB;
    const int kc2 = (t + 2) << 6;

    // phase A: read (cbuf, ks1) ahead; counted wait; MFMA ks0
    RD12(cbuf, c1, X1, W1);
    __builtin_amdgcn_sched_barrier(0);
    asm volatile("s_waitcnt lgkmcnt(12)" ::: "memory");
    __builtin_amdgcn_sched_barrier(0);
    MFMA32(X0, W0);

    // phase B: drain ALL my reads + stages BEFORE the barrier; barrier;
    // next-tile reads + kt+2 stages under MFMA ks1
    asm volatile("s_waitcnt vmcnt(0) lgkmcnt(0)" ::: "memory");
    __builtin_amdgcn_sched_barrier(0);
    __builtin_amdgcn_s_barrier();
    __builtin_amdgcn_sched_barrier(0);
    if (t < NKT - 1) RD12(nbuf, c0, X0, W0);
    if (t < NKT - 2) STAGE(ci, kc2);
    __builtin_amdgcn_sched_barrier(0);
    MFMA32(X1, W1);
  }

  // ---- epilogue: DIRECT dwordx4 stores from accumulators ----
  // acc[mf][nb]: frames gf0 + wr*128 + mf*16 + (l>>4)*4 + [0,4), bin = bin0 + wc*64 + nb*16 + (l&15)
  {
    const int bcol  = l & 15;
    const int fquad = (l >> 4) * 4;
#pragma unroll
    for (int mf = 0; mf < 8; ++mf) {
      const int gf = gf0 + wr * 128 + mf * 16 + fquad;
      const int bb = gf / NFRAMES;
      const int fr = gf - bb * NFRAMES;
#pragma unroll
      for (int nb = 0; nb < 4; ++nb) {
        const int bin = bin0 + wc * 64 + nb * 16 + bcol;
        if (fr <= NFRAMES - 4) {     // all 4 frames in same batch row
          size_t rowbase;
          if (bin < FBIN) rowbase = ((size_t)bb * FBIN + bin) * NFRAMES;
          else            rowbase = TOTOUT + ((size_t)bb * FBIN + (bin - FBIN)) * NFRAMES;
          *reinterpret_cast<f32x4u*>(out + rowbase + fr) = acc[mf][nb];
        } else {                     // straddles batch boundary (rare)
#pragma unroll
          for (int r = 0; r < 4; ++r) {
            const int gfr = gf + r;
            const int bbr = gfr / NFRAMES;
            const int frr = gfr - bbr * NFRAMES;
            size_t rb;
            if (bin < FBIN) rb = ((size_t)bbr * FBIN + bin) * NFRAMES;
            else            rb = TOTOUT + ((size_t)bbr * FBIN + (bin - FBIN)) * NFRAMES;
            out[rb + frr] = acc[mf][nb][r];
          }
        }
      }
    }
  }
#undef STAGE
#undef RD12
#undef MFMA32
}

// ---- exact f32 direct kernel: fallback only ----
__global__ void stft_direct_kernel(const float* __restrict__ x, const float* __restrict__ W,
                                   float* __restrict__ out,
                                   int bin_lo, int nbins, int fr_lo, int nframes) {
  long long total = (long long)NBATCH * nbins * nframes;
  for (long long t = (long long)blockIdx.x * blockDim.x + threadIdx.x; t < total;
       t += (long long)gridDim.x * blockDim.x) {
    int fr = fr_lo + (int)(t % nframes);
    long long q = t / nframes;
    int bin = bin_lo + (int)(q % nbins);
    int b   = (int)(q / nbins);
    const float* xb = x + (long long)b * XLEN;
    const float* wrow = W + (long long)bin * NFFT;
    float s = 0.f;
    const int base = fr * HOPSZ - (NFFT / 2);
    for (int j = 0; j < NFFT; ++j) {
      int xi = base + j;
      float xv = ((unsigned)xi < (unsigned)XLEN) ? xb[xi] : 0.f;
      s = fmaf(xv, wrow[j], s);
    }
    size_t off;
    if (bin < FBIN) off = ((size_t)b * FBIN + bin) * NFRAMES + fr;
    else            off = TOTOUT + ((size_t)b * FBIN + (bin - FBIN)) * NFRAMES + fr;
    out[off] = s;
  }
}

extern "C" void kernel_launch(void* const* d_in, const int* in_sizes, int n_in,
                              void* d_out, int out_size, void* d_ws, size_t ws_size,
                              hipStream_t stream) {
  const float* x = (const float*)d_in[0];
  const float* W = (const float*)d_in[1];
  float* out = (float*)d_out;

  const size_t xp_bytes = (size_t)NBATCH * PADLEN * sizeof(unsigned short);
  const size_t wb_bytes = (size_t)NBINS2 * NFFT * sizeof(unsigned short);

  if (ws_size >= xp_bytes + wb_bytes) {
    unsigned short* xp = (unsigned short*)d_ws;
    unsigned short* wb = (unsigned short*)((char*)d_ws + xp_bytes);

    prep_kernel<<<PREP_BLKS, 256, 0, stream>>>(x, W, xp, wb, out);
    stft_mfma8_kernel<<<NWG, 512, LDS_BYTES, stream>>>(xp, wb, out);
  } else {
    stft_direct_kernel<<<2048, 256, 0, stream>>>(x, W, out, 0, NBINS2, 0, NFRAMES);
  }
}

// Round 13
// 83.062 us; speedup vs baseline: 1.1553x; 1.1553x over previous
//
#include <hip/hip_runtime.h>
#include <hip/hip_bf16.h>

#define NFFT    1024
#define HOPSZ   256
#define XLEN    262144
#define PADLEN  (XLEN + NFFT)      // 263168
#define NBATCH  16
#define NBINS2  1026
#define FBIN    513
#define NFRAMES 1025
#define NGF     (NBATCH * NFRAMES) // 16400
#define TOTOUT  ((size_t)NBATCH * FBIN * NFRAMES)

// GEMM geometry: 256 bins x 128 frames per block, BK=32, 4 waves (1 per 64-bin strip)
#define KT 32                      // K elems per tile
#define NKT 32
#define NWG 512                    // 4 mt x 128 nt
#define BUFE 12288                 // elems per buffer: W 256x32=8192 + X 128x32=4096
#define BUFB 24576                 // bytes per buffer
#define LDS_BYTES (3 * BUFB)       // 73728 -> 2 blocks/CU
#define NTAIL  49184               // 2*16400 + 16*1024
#define PSTRIDE 132

typedef short bf16x8 __attribute__((ext_vector_type(8)));
typedef float f32x4  __attribute__((ext_vector_type(4)));
typedef float f32x2u __attribute__((ext_vector_type(2), aligned(4)));
typedef unsigned short u16x8 __attribute__((ext_vector_type(8)));
typedef unsigned short u16x4 __attribute__((ext_vector_type(4)));

__device__ __forceinline__ unsigned short f2bf(float f) {
  union { float f; unsigned u; } v; v.f = f;
  unsigned r = v.u + 0x7fffu + ((v.u >> 16) & 1u);   // RNE
  return (unsigned short)(r >> 16);
}
__device__ __forceinline__ float bf2f(unsigned short h) {
  union { unsigned u; float f; } v; v.u = ((unsigned)h) << 16; return v.f;
}

typedef __attribute__((address_space(1))) void void_g;
typedef __attribute__((address_space(3))) void void_l;
__device__ __forceinline__ void gload_lds16(const void* g, void* l) {
  __builtin_amdgcn_global_load_lds((void_g*)(g), (void_l*)(l), 16, 0, 0);
}

// ---- pack x -> bf16 with center padding ----
__global__ __launch_bounds__(256) void pack_x_kernel(const float* __restrict__ x,
                                                     unsigned short* __restrict__ xp) {
  long long t = (long long)blockIdx.x * 256 + threadIdx.x;
  long long base = t * 8;
  if (base >= (long long)NBATCH * PADLEN) return;
  int b   = (int)(base / PADLEN);
  int pos = (int)(base % PADLEN);
  const float* xb = x + (long long)b * XLEN;
  u16x8 v;
#pragma unroll
  for (int j = 0; j < 8; ++j) {
    int xi = pos + j - (NFFT / 2);
    float f = ((unsigned)xi < (unsigned)XLEN) ? xb[xi] : 0.0f;
    v[j] = f2bf(f);
  }
  *reinterpret_cast<u16x8*>(xp + base) = v;
}

// ---- pack W -> bf16 ----
__global__ __launch_bounds__(256) void pack_w_kernel(const float* __restrict__ W,
                                                     unsigned short* __restrict__ Wb) {
  long long t = ((long long)blockIdx.x * 256 + threadIdx.x) * 4;
  if (t >= (long long)NBINS2 * NFFT) return;
  float4 f = *reinterpret_cast<const float4*>(W + t);
  u16x4 v;
  v[0] = f2bf(f.x); v[1] = f2bf(f.y); v[2] = f2bf(f.z); v[3] = f2bf(f.w);
  *reinterpret_cast<u16x4*>(Wb + t) = v;
}

// ---- 256bin x 128frame GEMM, 4 waves, BK=32, 3-buffer ring, 2 blocks/CU.
//      Per iter: prefetch next frags (lgkm12) + stage tile t+2; drain own
//      vmcnt(0) before the single barrier (r9-proven cross-wave safety). ----
__global__ __launch_bounds__(256, 2) void stft_mfma4_kernel(const unsigned short* __restrict__ Xp,
                                                            const unsigned short* __restrict__ Wb,
                                                            float* __restrict__ out) {
  extern __shared__ unsigned short lds[];
  const int tid = threadIdx.x;
  const int l   = tid & 63;
  const int w   = tid >> 6;        // 0..3: wave's 64-bin strip
  const int r16 = l & 15, hi = l >> 4;

  // XCD swizzle: 512 = 8 xcd x 64; consecutive wgid share W panel (mt)
  const int bid  = blockIdx.x;
  const int wgid = (bid & 7) * 64 + (bid >> 3);
  const int mt   = wgid >> 7;       // 0..3
  const int nt   = wgid & 127;      // 0..127
  const int bin0 = mt * 256;
  const int gf0  = nt * 128;

  // ---- staging addressing (rows of 32 elems = 64B, 4x16B slots) ----
  const int lr = l >> 2;            // row within 16-row chunk
  const int ls = l & 3;             // 16B slot
  const int gsw = (lr >> 1) & 3;    // swizzle: slot s holds cols (s^gsw)*8
  const int cswz = ((ls ^ gsw) << 3);

  unsigned aqoff[4];                // W: wave w stages rows w*64 + qq*16 + lr
#pragma unroll
  for (int qq = 0; qq < 4; ++qq)
    aqoff[qq] = (unsigned)(bin0 + w * 64 + qq * 16 + lr) * NFFT + cswz;
  unsigned boff[2];                 // X: wave w stages rows w*32 + jj*16 + lr
#pragma unroll
  for (int jj = 0; jj < 2; ++jj) {
    const int gf = gf0 + w * 32 + jj * 16 + lr;    // < 16384
    const int bb = gf / NFRAMES;
    const int fr = gf - bb * NFRAMES;
    boff[jj] = (unsigned)bb * PADLEN + (unsigned)fr * HOPSZ + cswz;
  }

#define STAGE(D, KC) do { \
    _Pragma("unroll") \
    for (int q_ = 0; q_ < 4; ++q_) \
      gload_lds16(Wb + aqoff[q_] + (KC), lds + (D) * BUFE + (w * 4 + q_) * 512); \
    _Pragma("unroll") \
    for (int j_ = 0; j_ < 2; ++j_) \
      gload_lds16(Xp + boff[j_] + (KC), lds + (D) * BUFE + 8192 + (w * 2 + j_) * 512); \
    } while (0)

  // ---- fragment read bases (swizzled 16B slot = hi ^ ((r16>>1)&3)) ----
  const int swzb  = ((hi ^ ((r16 >> 1) & 3)) << 4);
  const int wbase = (w * 64 + r16) * 64 + swzb;        // byte within buffer
  const int xbase = 16384 + r16 * 64 + swzb;

#define RD12(DOFF, WARR, XARR) do { \
    _Pragma("unroll") \
    for (int n_ = 0; n_ < 4; ++n_) \
      WARR[n_] = *reinterpret_cast<const bf16x8*>((const char*)lds + (DOFF) + wbase + n_ * 1024); \
    _Pragma("unroll") \
    for (int m_ = 0; m_ < 8; ++m_) \
      XARR[m_] = *reinterpret_cast<const bf16x8*>((const char*)lds + (DOFF) + xbase + m_ * 1024); \
    } while (0)

#define MFMA32(WARR, XARR) do { \
    __builtin_amdgcn_s_setprio(1); \
    _Pragma("unroll") \
    for (int a_ = 0; a_ < 4; ++a_) { \
      _Pragma("unroll") \
      for (int b_ = 0; b_ < 8; ++b_) \
        acc[a_][b_] = __builtin_amdgcn_mfma_f32_16x16x32_bf16(WARR[a_], XARR[b_], acc[a_][b_], 0, 0, 0); \
    } \
    __builtin_amdgcn_s_setprio(0); } while (0)

#define ITER(NXTB, STGB, WIN, XIN, WOUT, XOUT) do { \
    RD12((NXTB) * BUFB, WOUT, XOUT); \
    __builtin_amdgcn_sched_barrier(0); \
    STAGE(STGB, kc); kc += KT; \
    asm volatile("s_waitcnt lgkmcnt(12)" ::: "memory"); \
    __builtin_amdgcn_sched_barrier(0); \
    MFMA32(WIN, XIN); \
    asm volatile("s_waitcnt vmcnt(0)" ::: "memory"); \
    __builtin_amdgcn_sched_barrier(0); \
    __builtin_amdgcn_s_barrier(); \
    __builtin_amdgcn_sched_barrier(0); \
    } while (0)

  f32x4 acc[4][8] = {};
  bf16x8 WA[4], XA[8], WB[4], XB[8];

  // ---- prologue: stage tiles 0,1; drain; barrier; read tile 0 frags ----
  STAGE(0, 0);
  STAGE(1, KT);
  asm volatile("s_waitcnt vmcnt(0)" ::: "memory");
  __builtin_amdgcn_sched_barrier(0);
  __builtin_amdgcn_s_barrier();
  __builtin_amdgcn_sched_barrier(0);
  RD12(0, WA, XA);

  int kc = 2 * KT;   // next tile to stage = tile 2
#pragma unroll 1
  for (int g = 0; g < 5; ++g) {    // t = 6g .. 6g+5  (0..29)
    ITER(1, 2, WA, XA, WB, XB);
    ITER(2, 0, WB, XB, WA, XA);
    ITER(0, 1, WA, XA, WB, XB);
    ITER(1, 2, WB, XB, WA, XA);
    ITER(2, 0, WA, XA, WB, XB);
    ITER(0, 1, WB, XB, WA, XA);
  }
  // t = 30: read tile 31 (buf1), MFMA tile 30
  RD12(1 * BUFB, WB, XB);
  asm volatile("s_waitcnt lgkmcnt(12)" ::: "memory");
  __builtin_amdgcn_sched_barrier(0);
  MFMA32(WA, XA);
  // t = 31
  asm volatile("s_waitcnt lgkmcnt(0)" ::: "memory");
  __builtin_amdgcn_sched_barrier(0);
  MFMA32(WB, XB);

  // ---- epilogue: 4 chunks of 64 bin-rows; LDS patch; 512B-contiguous streams ----
  {
    float* patch = (float*)lds;
    const int col   = l & 15;
    const int rbase = (l >> 4) * 4;
    // per-lane frame constants (2 floats per lane)
    const int gfE = gf0 + 2 * l;
    const int bbE = gfE / NFRAMES;
    const int frE = gfE - bbE * NFRAMES;
    const bool split = (frE == 1024);

#pragma unroll 1
    for (int c = 0; c < 4; ++c) {
      __builtin_amdgcn_s_barrier();
      if (w == c) {
#pragma unroll
        for (int a = 0; a < 4; ++a)
#pragma unroll
          for (int b = 0; b < 8; ++b)
#pragma unroll
            for (int r = 0; r < 4; ++r)
              patch[(a * 16 + rbase + r) * PSTRIDE + b * 16 + col] = acc[a][b][r];
      }
      __builtin_amdgcn_s_barrier();

#pragma unroll
      for (int i = 0; i < 16; ++i) {
        const int row = i * 4 + w;
        const int bin = bin0 + c * 64 + row;
        f32x2u v = *reinterpret_cast<const f32x2u*>(patch + row * PSTRIDE + 2 * l);
        size_t rowbase;
        if (bin < FBIN) rowbase = ((size_t)bbE * FBIN + bin) * NFRAMES;
        else            rowbase = TOTOUT + ((size_t)bbE * FBIN + (bin - FBIN)) * NFRAMES;
        if (!split) {
          *reinterpret_cast<f32x2u*>(out + rowbase + frE) = v;
        } else {
          size_t rowbase2;
          if (bin < FBIN) rowbase2 = ((size_t)(bbE + 1) * FBIN + bin) * NFRAMES;
          else            rowbase2 = TOTOUT + ((size_t)(bbE + 1) * FBIN + (bin - FBIN)) * NFRAMES;
          out[rowbase + 1024] = v[0];
          out[rowbase2]       = v[1];
        }
      }
    }
  }
#undef STAGE
#undef RD12
#undef MFMA32
#undef ITER
}

// ---- tail kernel: wave-per-output for leftover bins/frames ----
__global__ __launch_bounds__(512) void stft_tail_kernel(const unsigned short* __restrict__ Xp,
                                                        const unsigned short* __restrict__ Wb,
                                                        float* __restrict__ out) {
  const int wid = (int)((blockIdx.x * 512 + threadIdx.x) >> 6);
  const int l   = threadIdx.x & 63;
  if (wid >= NTAIL) return;
  int bin, gf;
  if (wid < 2 * NGF) { bin = 1024 + (wid & 1); gf = wid >> 1; }
  else { const int s = wid - 2 * NGF; gf = 16384 + (s & 15); bin = s >> 4; }
  const int bb = gf / NFRAMES;
  const int fr = gf - bb * NFRAMES;
  const unsigned short* xr = Xp + (size_t)bb * PADLEN + (size_t)fr * HOPSZ + l * 16;
  const unsigned short* wr = Wb + (size_t)bin * NFFT + l * 16;
  u16x8 x0 = *reinterpret_cast<const u16x8*>(xr);
  u16x8 x1 = *reinterpret_cast<const u16x8*>(xr + 8);
  u16x8 w0 = *reinterpret_cast<const u16x8*>(wr);
  u16x8 w1 = *reinterpret_cast<const u16x8*>(wr + 8);
  float s0 = 0.f, s1 = 0.f;
#pragma unroll
  for (int j = 0; j < 8; ++j) {
    s0 = fmaf(bf2f(x0[j]), bf2f(w0[j]), s0);
    s1 = fmaf(bf2f(x1[j]), bf2f(w1[j]), s1);
  }
  float s = s0 + s1;
#pragma unroll
  for (int k = 32; k >= 1; k >>= 1) s += __shfl_xor(s, k);
  if (l == 0) {
    size_t off;
    if (bin < FBIN) off = ((size_t)bb * FBIN + bin) * NFRAMES + fr;
    else            off = TOTOUT + ((size_t)bb * FBIN + (bin - FBIN)) * NFRAMES + fr;
    out[off] = s;
  }
}

// ---- exact f32 direct kernel: fallback only ----
__global__ void stft_direct_kernel(const float* __restrict__ x, const float* __restrict__ W,
                                   float* __restrict__ out,
                                   int bin_lo, int nbins, int fr_lo, int nframes) {
  long long total = (long long)NBATCH * nbins * nframes;
  for (long long t = (long long)blockIdx.x * blockDim.x + threadIdx.x; t < total;
       t += (long long)gridDim.x * blockDim.x) {
    int fr = fr_lo + (int)(t % nframes);
    long long q = t / nframes;
    int bin = bin_lo + (int)(q % nbins);
    int b   = (int)(q / nbins);
    const float* xb = x + (long long)b * XLEN;
    const float* wrow = W + (long long)bin * NFFT;
    float s = 0.f;
    const int base = fr * HOPSZ - (NFFT / 2);
    for (int j = 0; j < NFFT; ++j) {
      int xi = base + j;
      float xv = ((unsigned)xi < (unsigned)XLEN) ? xb[xi] : 0.f;
      s = fmaf(xv, wrow[j], s);
    }
    size_t off;
    if (bin < FBIN) off = ((size_t)b * FBIN + bin) * NFRAMES + fr;
    else            off = TOTOUT + ((size_t)b * FBIN + (bin - FBIN)) * NFRAMES + fr;
    out[off] = s;
  }
}

extern "C" void kernel_launch(void* const* d_in, const int* in_sizes, int n_in,
                              void* d_out, int out_size, void* d_ws, size_t ws_size,
                              hipStream_t stream) {
  const float* x = (const float*)d_in[0];
  const float* W = (const float*)d_in[1];
  float* out = (float*)d_out;

  const size_t xp_bytes = (size_t)NBATCH * PADLEN * sizeof(unsigned short);
  const size_t wb_bytes = (size_t)NBINS2 * NFFT * sizeof(unsigned short);

  if (ws_size >= xp_bytes + wb_bytes) {
    unsigned short* xp = (unsigned short*)d_ws;
    unsigned short* wb = (unsigned short*)((char*)d_ws + xp_bytes);

    {
      long long threads = (long long)NBATCH * PADLEN / 8;
      pack_x_kernel<<<(int)((threads + 255) / 256), 256, 0, stream>>>(x, xp);
    }
    pack_w_kernel<<<(NBINS2 * NFFT / 4 + 255) / 256, 256, 0, stream>>>(W, wb);

    stft_mfma4_kernel<<<NWG, 256, LDS_BYTES, stream>>>(xp, wb, out);
    stft_tail_kernel<<<NTAIL / 8, 512, 0, stream>>>(xp, wb, out);
  } else {
    stft_direct_kernel<<<2048, 256, 0, stream>>>(x, W, out, 0, NBINS2, 0, NFRAMES);
  }
}

// Round 14
// 66.351 us; speedup vs baseline: 1.4463x; 1.2519x over previous
//
#include <hip/hip_runtime.h>
#include <hip/hip_bf16.h>

#define NFFT    1024
#define HOPSZ   256
#define XLEN    262144
#define PADLEN  (XLEN + NFFT)      // 263168
#define NBATCH  16
#define NBINS2  1026
#define FBIN    513
#define NFRAMES 1025
#define NGF     (NBATCH * NFRAMES) // 16400
#define TOTOUT  ((size_t)NBATCH * FBIN * NFRAMES)

// GEMM geometry: 128 bins x 128 gf per block, BK=64, 4 waves (2 bin-halves x 2 gf-halves)
#define KT 64
#define NKT 16
#define NWG 1024                   // 8 mt x 128 nt
#define BUFE 16384                 // elems per buffer: W 128x64 + X 128x64
#define BUFB 32768                 // bytes per buffer
#define LDS_BYTES (2 * BUFB)       // 65536 -> 2 blocks/CU
#define NTAIL  49184               // 2*16400 + 16*1024
#define PSTRIDE 132

// fused pack kernel block ranges
#define PX_BLKS 2056               // NBATCH*PADLEN/8/256
#define PW_BLKS 1026               // NBINS2*NFFT/4/256

typedef short bf16x8 __attribute__((ext_vector_type(8)));
typedef float f32x4  __attribute__((ext_vector_type(4)));
typedef unsigned short u16x8 __attribute__((ext_vector_type(8)));
typedef unsigned short u16x4 __attribute__((ext_vector_type(4)));

__device__ __forceinline__ unsigned short f2bf(float f) {
  union { float f; unsigned u; } v; v.f = f;
  unsigned r = v.u + 0x7fffu + ((v.u >> 16) & 1u);   // RNE
  return (unsigned short)(r >> 16);
}
__device__ __forceinline__ float bf2f(unsigned short h) {
  union { unsigned u; float f; } v; v.u = ((unsigned)h) << 16; return v.f;
}

typedef __attribute__((address_space(1))) void void_g;
typedef __attribute__((address_space(3))) void void_l;
__device__ __forceinline__ void gload_lds16(const void* g, void* l) {
  __builtin_amdgcn_global_load_lds((void_g*)(g), (void_l*)(l), 16, 0, 0);
}

// ---- fused pack: x -> bf16 (padded) | W -> bf16 ----
__global__ __launch_bounds__(256) void pack_kernel(const float* __restrict__ x,
                                                   const float* __restrict__ W,
                                                   unsigned short* __restrict__ xp,
                                                   unsigned short* __restrict__ wb) {
  const int bid = blockIdx.x;
  const int tid = threadIdx.x;
  if (bid < PX_BLKS) {
    long long base = ((long long)bid * 256 + tid) * 8;
    int b   = (int)(base / PADLEN);
    int pos = (int)(base % PADLEN);
    const float* xb = x + (long long)b * XLEN;
    u16x8 v;
#pragma unroll
    for (int j = 0; j < 8; ++j) {
      int xi = pos + j - (NFFT / 2);
      float f = ((unsigned)xi < (unsigned)XLEN) ? xb[xi] : 0.0f;
      v[j] = f2bf(f);
    }
    *reinterpret_cast<u16x8*>(xp + base) = v;
  } else {
    long long t = (((long long)(bid - PX_BLKS)) * 256 + tid) * 4;
    float4 f = *reinterpret_cast<const float4*>(W + t);
    u16x4 v;
    v[0] = f2bf(f.x); v[1] = f2bf(f.y); v[2] = f2bf(f.z); v[3] = f2bf(f.w);
    *reinterpret_cast<u16x4*>(wb + t) = v;
  }
}

// ---- 128x128 GEMM, r9 schedule, 2 blocks/CU, X-locality XCD swizzle ----
__global__ __launch_bounds__(256, 2) void stft_mfma128_kernel(const unsigned short* __restrict__ Xp,
                                                              const unsigned short* __restrict__ Wb,
                                                              float* __restrict__ out) {
  extern __shared__ unsigned short lds[];
  const int tid = threadIdx.x;
  const int l   = tid & 63;
  const int w   = tid >> 6;        // 0..3
  const int wr  = w >> 1;          // bin half (64 bins)
  const int wc  = w & 1;           // gf half (64 frames)
  const int r16 = l & 15, hi = l >> 4;

  // XCD swizzle: each XCD owns all 8 mt x 16 nt; consecutive blocks vary mt
  // (share the X slab of one nt) -> X fetched once per XCD, W panels L2-hot.
  const int bid   = blockIdx.x;
  const int xcd   = bid & 7;
  const int local = bid >> 3;           // 0..127
  const int nt    = xcd * 16 + (local >> 3);
  const int mt    = local & 7;
  const int bin0  = mt * 128;
  const int gf0   = nt * 128;

  // staging (pre-swizzled global source)
  const int lr = l >> 3;
  const int ls = l & 7;
  const int cswz = ((ls ^ lr) << 3);

  unsigned aqoff[4], boff[4];
#pragma unroll
  for (int q = 0; q < 4; ++q)
    aqoff[q] = (unsigned)(bin0 + (w * 4 + q) * 8 + lr) * NFFT + cswz;
#pragma unroll
  for (int j = 0; j < 4; ++j) {
    const int gf = gf0 + (w * 4 + j) * 8 + lr;     // < 16384
    const int bb = gf / NFRAMES;
    const int fr = gf - bb * NFRAMES;
    boff[j] = (unsigned)bb * PADLEN + (unsigned)fr * HOPSZ + cswz;
  }

#define STAGE(D, KC) do { \
    _Pragma("unroll") \
    for (int q_ = 0; q_ < 4; ++q_) \
      gload_lds16(Wb + aqoff[q_] + (KC), lds + (D) * BUFE + (w * 4 + q_) * 512); \
    _Pragma("unroll") \
    for (int j_ = 0; j_ < 4; ++j_) \
      gload_lds16(Xp + boff[j_] + (KC), lds + (D) * BUFE + 8192 + (w * 4 + j_) * 512); \
    } while (0)

  // fragment read bases (T2 XOR-swizzle, 128B rows, 8x16B slots)
  const int aB0 = (wr * 64 + r16) * 128;
  const int bB0 = 16384 + (wc * 64 + r16) * 128;
  const int swz = (r16 & 7) << 4;
  const int c0  = (hi * 16) ^ swz;
  const int c1  = (64 + hi * 16) ^ swz;

#define RD8(BASE, C, AARR, BARR) do { \
    _Pragma("unroll") \
    for (int n_ = 0; n_ < 4; ++n_) \
      BARR[n_] = *reinterpret_cast<const bf16x8*>((const char*)(BASE) + bB0 + n_ * 2048 + (C)); \
    _Pragma("unroll") \
    for (int m_ = 0; m_ < 4; ++m_) \
      AARR[m_] = *reinterpret_cast<const bf16x8*>((const char*)(BASE) + aB0 + m_ * 2048 + (C)); \
    } while (0)

#define MFMA16(AARR, BARR) do { \
    __builtin_amdgcn_s_setprio(1); \
    _Pragma("unroll") \
    for (int m_ = 0; m_ < 4; ++m_) { \
      _Pragma("unroll") \
      for (int n_ = 0; n_ < 4; ++n_) \
        acc[m_][n_] = __builtin_amdgcn_mfma_f32_16x16x32_bf16(AARR[m_], BARR[n_], acc[m_][n_], 0, 0, 0); \
    } \
    __builtin_amdgcn_s_setprio(0); } while (0)

  f32x4 acc[4][4] = {};
  bf16x8 A0[4], B0[4], A1[4], B1[4];

  // ---- prologue: stage kt0->buf0, kt1->buf1; kt0 visible; read (buf0,ks0) ----
  STAGE(0, 0);
  STAGE(1, KT);
  asm volatile("s_waitcnt vmcnt(8)" ::: "memory");
  __builtin_amdgcn_s_barrier();
  __builtin_amdgcn_sched_barrier(0);
  RD8(lds, c0, A0, B0);

#pragma unroll 1
  for (int t = 0; t < NKT; ++t) {
    const int ci = t & 1;
    const char* cbuf = (const char*)lds + ci * BUFB;
    const char* nbuf = (const char*)lds + (ci ^ 1) * BUFB;
    const int kc2 = (t + 2) << 6;

    // phase A: read (cbuf, ks1) ahead; counted wait; MFMA ks0
    RD8(cbuf, c1, A1, B1);
    __builtin_amdgcn_sched_barrier(0);
    asm volatile("s_waitcnt lgkmcnt(8)" ::: "memory");
    __builtin_amdgcn_sched_barrier(0);
    MFMA16(A0, B0);

    // phase B: drain own reads+stages BEFORE barrier (cross-wave safety);
    // barrier; next-tile reads + kt+2 stages under MFMA ks1
    asm volatile("s_waitcnt vmcnt(0) lgkmcnt(0)" ::: "memory");
    __builtin_amdgcn_sched_barrier(0);
    __builtin_amdgcn_s_barrier();
    __builtin_amdgcn_sched_barrier(0);
    if (t < NKT - 1) RD8(nbuf, c0, A0, B0);
    if (t < NKT - 2) STAGE(ci, kc2);
    __builtin_amdgcn_sched_barrier(0);
    MFMA16(A1, B1);
  }

  // ---- epilogue: 2 chunks of 64 bin-rows; LDS patch; 256B-contiguous streams ----
  {
    float* patch = (float*)lds;
    const int col   = l & 15;
    const int rbase = (l >> 4) * 4;
    const int colbase = wc * 64;

    size_t baseR[2];
#pragma unroll
    for (int j = 0; j < 2; ++j) {
      const int gf = gf0 + j * 64 + l;
      const int bb = gf / NFRAMES;
      const int fr = gf - bb * NFRAMES;
      baseR[j] = (size_t)bb * FBIN * NFRAMES + fr;
    }

#pragma unroll
    for (int c = 0; c < 2; ++c) {
      __builtin_amdgcn_s_barrier();
      if (wr == c) {
#pragma unroll
        for (int m = 0; m < 4; ++m)
#pragma unroll
          for (int n = 0; n < 4; ++n)
#pragma unroll
            for (int r = 0; r < 4; ++r)
              patch[(m * 16 + rbase + r) * PSTRIDE + colbase + n * 16 + col] = acc[m][n][r];
      }
      __builtin_amdgcn_s_barrier();

      for (int i = 0; i < 16; ++i) {
        const int row = i * 4 + w;
        const int bin = bin0 + c * 64 + row;
        const size_t binoff = (size_t)bin * NFRAMES;
#pragma unroll
        for (int j = 0; j < 2; ++j) {
          const float v = patch[row * PSTRIDE + j * 64 + l];
          size_t off = binoff + (bin < FBIN ? baseR[j]
                                            : baseR[j] + TOTOUT - (size_t)FBIN * NFRAMES);
          out[off] = v;
        }
      }
    }
  }
#undef STAGE
#undef RD8
#undef MFMA16
}

// ---- tail kernel: wave-per-output for leftover bins/frames ----
__global__ __launch_bounds__(512) void stft_tail_kernel(const unsigned short* __restrict__ Xp,
                                                        const unsigned short* __restrict__ Wb,
                                                        float* __restrict__ out) {
  const int wid = (int)((blockIdx.x * 512 + threadIdx.x) >> 6);
  const int l   = threadIdx.x & 63;
  if (wid >= NTAIL) return;
  int bin, gf;
  if (wid < 2 * NGF) { bin = 1024 + (wid & 1); gf = wid >> 1; }
  else { const int s = wid - 2 * NGF; gf = 16384 + (s & 15); bin = s >> 4; }
  const int bb = gf / NFRAMES;
  const int fr = gf - bb * NFRAMES;
  const unsigned short* xr = Xp + (size_t)bb * PADLEN + (size_t)fr * HOPSZ + l * 16;
  const unsigned short* wr = Wb + (size_t)bin * NFFT + l * 16;
  u16x8 x0 = *reinterpret_cast<const u16x8*>(xr);
  u16x8 x1 = *reinterpret_cast<const u16x8*>(xr + 8);
  u16x8 w0 = *reinterpret_cast<const u16x8*>(wr);
  u16x8 w1 = *reinterpret_cast<const u16x8*>(wr + 8);
  float s0 = 0.f, s1 = 0.f;
#pragma unroll
  for (int j = 0; j < 8; ++j) {
    s0 = fmaf(bf2f(x0[j]), bf2f(w0[j]), s0);
    s1 = fmaf(bf2f(x1[j]), bf2f(w1[j]), s1);
  }
  float s = s0 + s1;
#pragma unroll
  for (int k = 32; k >= 1; k >>= 1) s += __shfl_xor(s, k);
  if (l == 0) {
    size_t off;
    if (bin < FBIN) off = ((size_t)bb * FBIN + bin) * NFRAMES + fr;
    else            off = TOTOUT + ((size_t)bb * FBIN + (bin - FBIN)) * NFRAMES + fr;
    out[off] = s;
  }
}

// ---- exact f32 direct kernel: fallback only ----
__global__ void stft_direct_kernel(const float* __restrict__ x, const float* __restrict__ W,
                                   float* __restrict__ out,
                                   int bin_lo, int nbins, int fr_lo, int nframes) {
  long long total = (long long)NBATCH * nbins * nframes;
  for (long long t = (long long)blockIdx.x * blockDim.x + threadIdx.x; t < total;
       t += (long long)gridDim.x * blockDim.x) {
    int fr = fr_lo + (int)(t % nframes);
    long long q = t / nframes;
    int bin = bin_lo + (int)(q % nbins);
    int b   = (int)(q / nbins);
    const float* xb = x + (long long)b * XLEN;
    const float* wrow = W + (long long)bin * NFFT;
    float s = 0.f;
    const int base = fr * HOPSZ - (NFFT / 2);
    for (int j = 0; j < NFFT; ++j) {
      int xi = base + j;
      float xv = ((unsigned)xi < (unsigned)XLEN) ? xb[xi] : 0.f;
      s = fmaf(xv, wrow[j], s);
    }
    size_t off;
    if (bin < FBIN) off = ((size_t)b * FBIN + bin) * NFRAMES + fr;
    else            off = TOTOUT + ((size_t)b * FBIN + (bin - FBIN)) * NFRAMES + fr;
    out[off] = s;
  }
}

extern "C" void kernel_launch(void* const* d_in, const int* in_sizes, int n_in,
                              void* d_out, int out_size, void* d_ws, size_t ws_size,
                              hipStream_t stream) {
  const float* x = (const float*)d_in[0];
  const float* W = (const float*)d_in[1];
  float* out = (float*)d_out;

  const size_t xp_bytes = (size_t)NBATCH * PADLEN * sizeof(unsigned short);
  const size_t wb_bytes = (size_t)NBINS2 * NFFT * sizeof(unsigned short);

  if (ws_size >= xp_bytes + wb_bytes) {
    unsigned short* xp = (unsigned short*)d_ws;
    unsigned short* wb = (unsigned short*)((char*)d_ws + xp_bytes);

    pack_kernel<<<PX_BLKS + PW_BLKS, 256, 0, stream>>>(x, W, xp, wb);
    stft_mfma128_kernel<<<NWG, 256, LDS_BYTES, stream>>>(xp, wb, out);
    stft_tail_kernel<<<NTAIL / 8, 512, 0, stream>>>(xp, wb, out);
  } else {
    stft_direct_kernel<<<2048, 256, 0, stream>>>(x, W, out, 0, NBINS2, 0, NFRAMES);
  }
}